// Round 5
// baseline (275.289 us; speedup 1.0000x reference)
//
#include <hip/hip_runtime.h>

#define BB 8
#define LL 2048
#define DD 256

typedef _Float16 half8 __attribute__((ext_vector_type(8)));
typedef float floatx4 __attribute__((ext_vector_type(4)));
typedef unsigned short ushort8 __attribute__((ext_vector_type(8)));
typedef unsigned short ushort4v __attribute__((ext_vector_type(4)));

__device__ inline unsigned short f2h(float f) {
  _Float16 h = (_Float16)f;
  return __builtin_bit_cast(unsigned short, h);
}

// async global->LDS DMA, 16B per lane; LDS dest = uniform base + lane*16
__device__ inline void gll(const void* g, void* l) {
  __builtin_amdgcn_global_load_lds(
      (const __attribute__((address_space(1))) unsigned int*)g,
      (__attribute__((address_space(3))) unsigned int*)l, 16, 0, 0);
}

// K image: per 32-kv tile, rows padded to 272 f16, 16B-chunk c stored at
// c ^ (row&7).  tile = 8704 f16 = 17408 B = 17 KB-chunks.
// V image: per 32-kv tile, [256 d][36 f16] (cols 0..31 = kv).  18432 B.
#define KT_F16 8704
#define VT_F16 9216

// ---------------------------------------------------------------------------
// Kernel 0: W fp32 -> fp16, Wh[3][256][256].
// ---------------------------------------------------------------------------
__global__ __launch_bounds__(256) void wcvt(
    const float* __restrict__ Wq, const float* __restrict__ Wk,
    const float* __restrict__ Wv, unsigned short* __restrict__ Wh) {
  const int bm = blockIdx.x >> 5;
  const float* src = (bm == 0) ? Wq : (bm == 1) ? Wk : Wv;
  const int off = (blockIdx.x & 31) * 2048 + threadIdx.x * 8;
  float4 a = *(const float4*)(src + off);
  float4 b = *(const float4*)(src + off + 4);
  ushort8 u = {f2h(a.x), f2h(a.y), f2h(a.z), f2h(a.w),
               f2h(b.x), f2h(b.y), f2h(b.z), f2h(b.w)};
  *(ushort8*)(Wh + bm * 65536 + off) = u;
}

// ---------------------------------------------------------------------------
// Kernel 1: fused QKV projection.  grid 512 (32-row tiles), block 256.
// Epilogue: C-frags -> per-wave LDS tile -> coalesced b64 stores into the
// swizzled K/V images (Q plain [l][d]).
// ---------------------------------------------------------------------------
__global__ __launch_bounds__(256) void proj(
    const float* __restrict__ x, const unsigned short* __restrict__ Wh,
    unsigned short* __restrict__ Qb, unsigned short* __restrict__ Kimg,
    unsigned short* __restrict__ Vimg) {
  __shared__ unsigned short Tw[4][768];
  const int t = threadIdx.x;
  const int wave = t >> 6, lane = t & 63, quad = lane >> 4, m16 = lane & 15;
  const int l0g = blockIdx.x * 32;
  const size_t tile = l0g >> 5;  // global 32-row tile index (b*64 + ...)

  half8 xf[2][8];
  for (int mt = 0; mt < 2; ++mt) {
    const float* xp = x + (size_t)(l0g + mt * 16 + m16) * DD + quad * 8;
    for (int kb = 0; kb < 8; ++kb) {
      float4 a = *(const float4*)(xp + kb * 32);
      float4 c = *(const float4*)(xp + kb * 32 + 4);
      ushort8 u = {f2h(a.x), f2h(a.y), f2h(a.z), f2h(a.w),
                   f2h(c.x), f2h(c.y), f2h(c.z), f2h(c.w)};
      xf[mt][kb] = __builtin_bit_cast(half8, u);
    }
  }

  unsigned short* T = Tw[wave];
  for (int j = 0; j < 12; ++j) {
    const int nt = wave * 12 + j;
    const int mat = nt >> 4, ot = nt & 15;
    const unsigned short* wp =
        Wh + mat * 65536 + (ot * 16 + m16) * DD + quad * 8;
    floatx4 acc[2] = {{0, 0, 0, 0}, {0, 0, 0, 0}};
    if (mat < 2) {
      for (int kb = 0; kb < 8; ++kb) {
        half8 wf = __builtin_bit_cast(half8, *(const ushort8*)(wp + kb * 32));
        acc[0] = __builtin_amdgcn_mfma_f32_16x16x32_f16(xf[0][kb], wf, acc[0], 0, 0, 0);
        acc[1] = __builtin_amdgcn_mfma_f32_16x16x32_f16(xf[1][kb], wf, acc[1], 0, 0, 0);
      }
      // tile [32 l][20 cols(16 used)]: row = mt*16+quad*4+r, col = m16
      for (int mt = 0; mt < 2; ++mt)
        for (int r = 0; r < 4; ++r)
          T[(mt * 16 + quad * 4 + r) * 20 + m16] = f2h(acc[mt][r]);
      __builtin_amdgcn_s_waitcnt(0);  // lgkm: wave-private LDS RAW
      for (int h = 0; h < 2; ++h) {
        int c4 = (lane >> 5) + h * 2;  // 8B chunk 0..3 of the 16 cols
        int row = lane & 31;
        ushort4v v = *(const ushort4v*)&T[row * 20 + c4 * 4];
        if (mat == 0) {
          *(ushort4v*)(Qb + (size_t)(l0g + row) * DD + ot * 16 + c4 * 4) = v;
        } else {
          int c16 = (ot * 2 + (c4 >> 1)) ^ (row & 7);
          *(ushort4v*)(Kimg + tile * KT_F16 + row * 272 + c16 * 8 +
                       (c4 & 1) * 4) = v;
        }
      }
    } else {
      for (int kb = 0; kb < 8; ++kb) {
        half8 wf = __builtin_bit_cast(half8, *(const ushort8*)(wp + kb * 32));
        acc[0] = __builtin_amdgcn_mfma_f32_16x16x32_f16(wf, xf[0][kb], acc[0], 0, 0, 0);
        acc[1] = __builtin_amdgcn_mfma_f32_16x16x32_f16(wf, xf[1][kb], acc[1], 0, 0, 0);
      }
      // tile [16 o][36 cols(32 l used)]: row = quad*4+r (o), col = mt*16+m16
      for (int mt = 0; mt < 2; ++mt)
        for (int r = 0; r < 4; ++r)
          T[(quad * 4 + r) * 36 + mt * 16 + m16] = f2h(acc[mt][r]);
      __builtin_amdgcn_s_waitcnt(0);
      for (int h = 0; h < 2; ++h) {
        int c4 = (lane >> 4) + h * 4;  // 8B chunk 0..7 of 32 l-cols
        int row = lane & 15;           // o within tile
        ushort4v v = *(const ushort4v*)&T[row * 36 + c4 * 4];
        *(ushort4v*)(Vimg + tile * VT_F16 + (ot * 16 + row) * 36 + c4 * 4) = v;
      }
    }
  }
}

// ---------------------------------------------------------------------------
// Kernel 2: flash attention.  512 thr = 8 waves = 2 qw (32 q-rows each) x
// 4 grp (kv-split, 32 kv each -> 128 kv/iter).  grid (32,8) = 1 block/CU.
// K/V staged by global_load_lds from pre-swizzled images; 4-way LDS merge.
// ---------------------------------------------------------------------------
__global__ __launch_bounds__(512, 2) void attn(
    const unsigned short* __restrict__ Qb, const unsigned short* __restrict__ Kimg,
    const unsigned short* __restrict__ Vimg, const int* __restrict__ lens,
    float* __restrict__ out) {
  // [0, 69632): Ks 4 x 17408   [69632, 143360): Vs 4 x 18432
  // [143360, 161792): Ps 8 waves x 32 x 36 f16
  __shared__ __attribute__((aligned(16))) unsigned char smem[161792];
  const int t = threadIdx.x;
  const int wave = t >> 6, lane = t & 63, quad = lane >> 4, m16 = lane & 15;
  const int qw = wave & 1, grp = wave >> 1;
  unsigned short* Ks = (unsigned short*)(smem + grp * 17408);
  unsigned short* Vs = (unsigned short*)(smem + 69632 + grp * 18432);
  unsigned short* Pw = (unsigned short*)(smem + 143360 + wave * 2304);

  const int b = blockIdx.y;
  const int q0 = blockIdx.x * 64;
  const int len = lens[b];
  const size_t baseQ = (size_t)b * LL * DD;
  const unsigned short* KimgB = Kimg + (size_t)b * 64 * KT_F16;
  const unsigned short* VimgB = Vimg + (size_t)b * 64 * VT_F16;

  // Q frags: 32 rows (2 m-subtiles) for this wave
  half8 af[2][8];
  for (int mt = 0; mt < 2; ++mt) {
    const unsigned short* qrow =
        Qb + baseQ + (size_t)(q0 + qw * 32 + mt * 16 + m16) * DD + quad * 8;
    for (int kb = 0; kb < 8; ++kb)
      af[mt][kb] = __builtin_bit_cast(half8, *(const ushort8*)(qrow + kb * 32));
  }

  floatx4 O[2][16];
  for (int mt = 0; mt < 2; ++mt)
    for (int i = 0; i < 16; ++i) O[mt][i] = (floatx4){0, 0, 0, 0};
  float mrow[2][4], lrow[2][4];
  for (int mt = 0; mt < 2; ++mt)
    for (int r = 0; r < 4; ++r) { mrow[mt][r] = -1e30f; lrow[mt][r] = 0.f; }

  auto prefetch = [&](int tile) {
    if (qw == 0) {
      const char* g = (const char*)(KimgB + (size_t)tile * KT_F16) + lane * 16;
      char* ld = (char*)Ks;
      for (int c = 0; c < 17; ++c) gll(g + c * 1024, ld + c * 1024);
    } else {
      const char* g = (const char*)(VimgB + (size_t)tile * VT_F16) + lane * 16;
      char* ld = (char*)Vs;
      for (int c = 0; c < 18; ++c) gll(g + c * 1024, ld + c * 1024);
    }
  };

  const int T = (len + 127) >> 7;
  prefetch(grp);

  for (int it = 0; it < T; ++it) {
    const int kv0 = it * 128 + grp * 32;
    __syncthreads();  // drains global_load_lds (vmcnt) + joins waves
    if (kv0 < len) {
      // S = Q K^T : 2 m x 2 n x 8 k
      floatx4 s[2][2];
      for (int mt = 0; mt < 2; ++mt)
        for (int n = 0; n < 2; ++n) s[mt][n] = (floatx4){0, 0, 0, 0};
      for (int kb = 0; kb < 8; ++kb)
        for (int n = 0; n < 2; ++n) {
          half8 kf = __builtin_bit_cast(
              half8, *(const ushort8*)&Ks[(n * 16 + m16) * 272 +
                                          (((kb * 4 + quad) ^ (m16 & 7)) * 8)]);
          s[0][n] = __builtin_amdgcn_mfma_f32_16x16x32_f16(af[0][kb], kf, s[0][n], 0, 0, 0);
          s[1][n] = __builtin_amdgcn_mfma_f32_16x16x32_f16(af[1][kb], kf, s[1][n], 0, 0, 0);
        }
      // scale + mask + online softmax
      bool moved = false;
      float al[2][4];
      for (int mt = 0; mt < 2; ++mt) {
        for (int n = 0; n < 2; ++n) {
          bool valid = (kv0 + n * 16 + m16) < len;
          for (int r = 0; r < 4; ++r)
            s[mt][n][r] = valid ? s[mt][n][r] * 0.0625f : -1e30f;
        }
        for (int r = 0; r < 4; ++r) {
          float v = fmaxf(s[mt][0][r], s[mt][1][r]);
          v = fmaxf(v, __shfl_xor(v, 1));
          v = fmaxf(v, __shfl_xor(v, 2));
          v = fmaxf(v, __shfl_xor(v, 4));
          v = fmaxf(v, __shfl_xor(v, 8));
          float mn = fmaxf(mrow[mt][r], v);
          al[mt][r] = __expf(mrow[mt][r] - mn);
          mrow[mt][r] = mn;
          moved |= (al[mt][r] != 1.f);
          float sum = 0.f;
          for (int n = 0; n < 2; ++n) {
            float p = __expf(s[mt][n][r] - mn);
            Pw[(mt * 16 + quad * 4 + r) * 36 + n * 16 + m16] = f2h(p);
            sum += p;
          }
          sum += __shfl_xor(sum, 1);
          sum += __shfl_xor(sum, 2);
          sum += __shfl_xor(sum, 4);
          sum += __shfl_xor(sum, 8);
          lrow[mt][r] = lrow[mt][r] * al[mt][r] + sum;
        }
      }
      if (__ballot(moved)) {
        for (int mt = 0; mt < 2; ++mt)
          for (int i = 0; i < 16; ++i)
            for (int r = 0; r < 4; ++r) O[mt][i][r] *= al[mt][r];
      }
      // PV: pf reused across all 16 n-blocks
      half8 pf[2];
      for (int mt = 0; mt < 2; ++mt)
        pf[mt] = __builtin_bit_cast(
            half8, *(const ushort8*)&Pw[(mt * 16 + m16) * 36 + quad * 8]);
      for (int nb = 0; nb < 16; ++nb) {
        half8 vf = __builtin_bit_cast(
            half8, *(const ushort8*)&Vs[(nb * 16 + m16) * 36 + quad * 8]);
        O[0][nb] = __builtin_amdgcn_mfma_f32_16x16x32_f16(pf[0], vf, O[0][nb], 0, 0, 0);
        O[1][nb] = __builtin_amdgcn_mfma_f32_16x16x32_f16(pf[1], vf, O[1][nb], 0, 0, 0);
      }
    }
    __syncthreads();  // all waves done reading this buffer
    if (it + 1 < T) prefetch((it + 1) * 4 + grp);
  }

  // ---- 4-way merge via LDS (aliases Ks/Vs) ----
  __syncthreads();
  float* bufA = (float*)smem;                    // [64][258] f32
  float* bufB = (float*)(smem + 69632);          // [64][258] f32
  float* Mm = (float*)(smem + 143360);           // [8][32]
  float* Ml = Mm + 256;                          // [8][32]

  auto dump = [&](float* buf, int slot) {
    for (int mt = 0; mt < 2; ++mt)
      for (int nb = 0; nb < 16; ++nb)
        for (int r = 0; r < 4; ++r)
          buf[(qw * 32 + mt * 16 + quad * 4 + r) * 258 + nb * 16 + m16] =
              O[mt][nb][r];
    if (m16 == 0)
      for (int mt = 0; mt < 2; ++mt)
        for (int r = 0; r < 4; ++r) {
          Mm[(slot * 2 + qw) * 32 + mt * 16 + quad * 4 + r] = mrow[mt][r];
          Ml[(slot * 2 + qw) * 32 + mt * 16 + quad * 4 + r] = lrow[mt][r];
        }
  };
  auto merge = [&](const float* buf, int slot) {
    for (int mt = 0; mt < 2; ++mt)
      for (int r = 0; r < 4; ++r) {
        int row = mt * 16 + quad * 4 + r;
        float mB = Mm[(slot * 2 + qw) * 32 + row];
        float lB = Ml[(slot * 2 + qw) * 32 + row];
        float m = fmaxf(mrow[mt][r], mB);
        float a = __expf(mrow[mt][r] - m);
        float bb = __expf(mB - m);
        mrow[mt][r] = m;
        lrow[mt][r] = lrow[mt][r] * a + lB * bb;
        for (int nb = 0; nb < 16; ++nb)
          O[mt][nb][r] = O[mt][nb][r] * a +
                         buf[(qw * 32 + row) * 258 + nb * 16 + m16] * bb;
      }
  };

  if (grp == 1) dump(bufA, 1);
  if (grp == 3) dump(bufB, 3);
  __syncthreads();
  if (grp == 0) merge(bufA, 1);
  if (grp == 2) merge(bufB, 3);
  __syncthreads();
  if (grp == 2) dump(bufA, 2);
  __syncthreads();
  if (grp == 0) {
    merge(bufA, 2);
    for (int mt = 0; mt < 2; ++mt)
      for (int r = 0; r < 4; ++r) {
        float inv = 1.f / lrow[mt][r];
        int row = q0 + qw * 32 + mt * 16 + quad * 4 + r;
        for (int nb = 0; nb < 16; ++nb)
          out[baseQ + (size_t)row * DD + nb * 16 + m16] = O[mt][nb][r] * inv;
      }
  }
}

extern "C" void kernel_launch(void* const* d_in, const int* in_sizes, int n_in,
                              void* d_out, int out_size, void* d_ws, size_t ws_size,
                              hipStream_t stream) {
  const float* x = (const float*)d_in[0];
  const float* Wq = (const float*)d_in[1];
  const float* Wk = (const float*)d_in[2];
  const float* Wv = (const float*)d_in[3];
  const int* lens = (const int*)d_in[4];
  unsigned short* Qb = (unsigned short*)d_ws;
  unsigned short* Kimg = Qb + (size_t)BB * LL * DD;            // 4.19M f16
  unsigned short* Vimg = Kimg + (size_t)BB * 64 * KT_F16;      // 4.46M f16
  unsigned short* Wh = Vimg + (size_t)BB * 64 * VT_F16;        // 4.72M f16
  float* out = (float*)d_out;

  wcvt<<<96, 256, 0, stream>>>(Wq, Wk, Wv, Wh);
  proj<<<512, 256, 0, stream>>>(x, Wh, Qb, Kimg, Vimg);
  attn<<<dim3(32, 8), 512, 0, stream>>>(Qb, Kimg, Vimg, lens, out);
}

// Round 6
// 205.237 us; speedup vs baseline: 1.3413x; 1.3413x over previous
//
#include <hip/hip_runtime.h>

#define BB 8
#define LL 2048
#define DD 256

typedef _Float16 half8 __attribute__((ext_vector_type(8)));
typedef float floatx4 __attribute__((ext_vector_type(4)));
typedef unsigned short ushort8 __attribute__((ext_vector_type(8)));
typedef unsigned short ushort4v __attribute__((ext_vector_type(4)));

__device__ inline unsigned short f2h(float f) {
  _Float16 h = (_Float16)f;
  return __builtin_bit_cast(unsigned short, h);
}
__device__ inline float h2fu(unsigned v) {
  return (float)__builtin_bit_cast(_Float16, (unsigned short)(v & 0xffff));
}

// ---------------------------------------------------------------------------
// Kernel 1: Q/K projection (R2-proven).  Out[l][d] fp16.
// ---------------------------------------------------------------------------
__global__ __launch_bounds__(256) void qk_proj(
    const float* __restrict__ x,
    const float* __restrict__ Wq, const float* __restrict__ Wk,
    unsigned short* __restrict__ Qb, unsigned short* __restrict__ Kb) {
  __shared__ __attribute__((aligned(16))) unsigned short Xs[64 * 264];
  __shared__ __attribute__((aligned(16))) unsigned short Ws[32 * 264];
  const int t = threadIdx.x;
  const int wave = t >> 6, lane = t & 63, quad = lane >> 4, m16 = lane & 15;
  const int r0 = blockIdx.x * 64;
  const float* W = (blockIdx.y == 0) ? Wq : Wk;
  unsigned short* Out = (blockIdx.y == 0) ? Qb : Kb;

  for (int p = 0; p < 16; ++p) {
    int idx = p * 1024 + t * 4;
    int row = idx >> 8, col = idx & 255;
    float4 v = *(const float4*)(x + (size_t)(r0 + row) * DD + col);
    ushort4v h = {f2h(v.x), f2h(v.y), f2h(v.z), f2h(v.w)};
    *(ushort4v*)&Xs[row * 264 + col] = h;
  }
  __syncthreads();

  half8 af[8];
  for (int kb = 0; kb < 8; ++kb)
    af[kb] = __builtin_bit_cast(
        half8, *(const ushort8*)&Xs[(wave * 16 + m16) * 264 + kb * 32 + quad * 8]);

  for (int c = 0; c < 8; ++c) {
    if (c) __syncthreads();
    for (int p = 0; p < 8; ++p) {
      int idx = p * 1024 + t * 4;
      int row = idx >> 8, col = idx & 255;
      float4 v = *(const float4*)(W + (size_t)(c * 32 + row) * DD + col);
      ushort4v h = {f2h(v.x), f2h(v.y), f2h(v.z), f2h(v.w)};
      *(ushort4v*)&Ws[row * 264 + col] = h;
    }
    __syncthreads();
    floatx4 acc[2] = {{0, 0, 0, 0}, {0, 0, 0, 0}};
    for (int n = 0; n < 2; ++n)
      for (int kb = 0; kb < 8; ++kb) {
        half8 bf = __builtin_bit_cast(
            half8,
            *(const ushort8*)&Ws[(n * 16 + m16) * 264 + kb * 32 + quad * 8]);
        acc[n] = __builtin_amdgcn_mfma_f32_16x16x32_f16(af[kb], bf, acc[n], 0, 0, 0);
      }
    for (int n = 0; n < 2; ++n)
      for (int r = 0; r < 4; ++r) {
        int rowg = r0 + wave * 16 + quad * 4 + r;
        int colg = c * 32 + n * 16 + m16;
        Out[(size_t)rowg * DD + colg] = f2h(acc[n][r]);
      }
  }
}

// ---------------------------------------------------------------------------
// Kernel 1b: V projection writing V TRANSPOSED VT[b][d][l] (R2-proven).
// ---------------------------------------------------------------------------
__global__ __launch_bounds__(256) void vproj_t(
    const float* __restrict__ x, const float* __restrict__ Wv,
    unsigned short* __restrict__ VT) {
  __shared__ __attribute__((aligned(16))) unsigned short Xs[64 * 264];
  __shared__ __attribute__((aligned(16))) unsigned short Ws[64 * 264];
  const int t = threadIdx.x;
  const int wave = t >> 6, lane = t & 63, quad = lane >> 4, m16 = lane & 15;
  const int l0 = blockIdx.x * 64;
  const int b = l0 >> 11, lb = l0 & 2047;

  for (int p = 0; p < 16; ++p) {
    int idx = p * 1024 + t * 4;
    int row = idx >> 8, col = idx & 255;
    float4 v = *(const float4*)(x + (size_t)(l0 + row) * DD + col);
    ushort4v h = {f2h(v.x), f2h(v.y), f2h(v.z), f2h(v.w)};
    *(ushort4v*)&Xs[row * 264 + col] = h;
  }
  __syncthreads();

  half8 xf[8];
  for (int kb = 0; kb < 8; ++kb)
    xf[kb] = __builtin_bit_cast(
        half8, *(const ushort8*)&Xs[(wave * 16 + m16) * 264 + kb * 32 + quad * 8]);

  for (int c = 0; c < 4; ++c) {
    if (c) __syncthreads();
    for (int p = 0; p < 16; ++p) {
      int idx = p * 1024 + t * 4;
      int row = idx >> 8, col = idx & 255;
      float4 v = *(const float4*)(Wv + (size_t)(c * 64 + row) * DD + col);
      ushort4v h = {f2h(v.x), f2h(v.y), f2h(v.z), f2h(v.w)};
      *(ushort4v*)&Ws[row * 264 + col] = h;
    }
    __syncthreads();
    for (int mt = 0; mt < 4; ++mt) {
      floatx4 acc = {0, 0, 0, 0};
      for (int kb = 0; kb < 8; ++kb) {
        half8 af = __builtin_bit_cast(
            half8,
            *(const ushort8*)&Ws[(mt * 16 + m16) * 264 + kb * 32 + quad * 8]);
        acc = __builtin_amdgcn_mfma_f32_16x16x32_f16(af, xf[kb], acc, 0, 0, 0);
      }
      int o = c * 64 + mt * 16 + quad * 4;
      int l = lb + wave * 16 + m16;
      for (int r = 0; r < 4; ++r)
        VT[((size_t)(b * DD + o + r)) * LL + l] = f2h(acc[r]);
    }
  }
}

// ---------------------------------------------------------------------------
// Kernel 2: flash attention, kv split ACROSS blocks (z = half: [0,1024) /
// [1024,len)).  256 thr = 4 q-waves x 16 rows, kv 64/iter, register-dbuf
// staging.  grid (32,8,2) = 512 blocks = 2 independent blocks/CU (LDS 77KB).
// Partials: O as f16 packed into d_out (lo=half0, hi=half1); m,l in ws.
// ---------------------------------------------------------------------------
__global__ __launch_bounds__(256, 2) void attn(
    const unsigned short* __restrict__ Qb, const unsigned short* __restrict__ Kb,
    const unsigned short* __restrict__ VT, const int* __restrict__ lens,
    float* __restrict__ out, float* __restrict__ ml0, float* __restrict__ ml1) {
  // [0,32768): Ks 64x256 (XOR-swizzled chunks)
  // [32768,69632): Vs 256x72 (64 kv + 8 pad)
  // [69632,78848): Ps 4 waves x 16 x 72
  __shared__ __attribute__((aligned(16))) unsigned char smem[78848];
  const int t = threadIdx.x;
  const int wave = t >> 6, lane = t & 63, quad = lane >> 4, m16 = lane & 15;
  unsigned short* Ks = (unsigned short*)smem;
  unsigned short* Vs = (unsigned short*)(smem + 32768);
  unsigned short* Pw = (unsigned short*)(smem + 69632 + wave * 2304);

  const int b = blockIdx.y;
  const int q0 = blockIdx.x * 64;
  const int half = blockIdx.z;
  const int len = lens[b];
  const int kv_lo = half << 10;
  const int kv_hi = min(len, kv_lo + 1024);
  const int T = (kv_hi - kv_lo + 63) >> 6;  // 0..16
  const size_t base = (size_t)b * LL * DD;
  const unsigned short* kbase = Kb + base;
  const unsigned short* vbase = VT + (size_t)b * DD * LL;

  half8 qf[8];
  {
    const unsigned short* qrow =
        Qb + base + (size_t)(q0 + wave * 16 + m16) * DD + quad * 8;
    for (int kb = 0; kb < 8; ++kb)
      qf[kb] = __builtin_bit_cast(half8, *(const ushort8*)(qrow + kb * 32));
  }

  floatx4 O[16];
  for (int i = 0; i < 16; ++i) O[i] = (floatx4){0, 0, 0, 0};
  float mrow[4] = {-1e30f, -1e30f, -1e30f, -1e30f};
  float lrow[4] = {0.f, 0.f, 0.f, 0.f};

  ushort8 kreg[8], vreg[8];
#define LOAD_TILES(KV0)                                                     \
  for (int c = 0; c < 8; ++c) {                                             \
    int ch = c * 256 + t;                                                   \
    kreg[c] = *(const ushort8*)(kbase + (size_t)((KV0) + (ch >> 5)) * DD +  \
                                (ch & 31) * 8);                             \
    vreg[c] = *(const ushort8*)(vbase + (size_t)(ch >> 3) * LL + (KV0) +    \
                                (ch & 7) * 8);                              \
  }

  if (T) LOAD_TILES(kv_lo);

  for (int it = 0; it < T; ++it) {
    const int kv0 = kv_lo + it * 64;
    __syncthreads();  // all waves done reading previous tile
    for (int c = 0; c < 8; ++c) {
      int ch = c * 256 + t;
      int row = ch >> 5, cc = ch & 31;
      *(ushort8*)&Ks[row * 256 + ((cc ^ (row & 7)) * 8)] = kreg[c];
      int d = ch >> 3, c8 = ch & 7;
      *(ushort8*)&Vs[d * 72 + c8 * 8] = vreg[c];
    }
    __syncthreads();  // LDS visible
    if (it + 1 < T) LOAD_TILES(kv0 + 64);  // overlaps compute below

    // S = Q K^T : 4 n-tiles x 8 k-steps
    floatx4 s[4];
    for (int n = 0; n < 4; ++n) s[n] = (floatx4){0, 0, 0, 0};
    for (int kb = 0; kb < 8; ++kb)
      for (int n = 0; n < 4; ++n) {
        half8 kf = __builtin_bit_cast(
            half8, *(const ushort8*)&Ks[(n * 16 + m16) * 256 +
                                        (((kb * 4 + quad) ^ (m16 & 7)) * 8)]);
        s[n] = __builtin_amdgcn_mfma_f32_16x16x32_f16(qf[kb], kf, s[n], 0, 0, 0);
      }
    // scale + mask + online softmax
    for (int n = 0; n < 4; ++n) {
      bool valid = (kv0 + n * 16 + m16) < kv_hi;
      for (int r = 0; r < 4; ++r)
        s[n][r] = valid ? s[n][r] * 0.0625f : -1e30f;
    }
    bool moved = false;
    float al[4];
    for (int r = 0; r < 4; ++r) {
      float v = fmaxf(fmaxf(s[0][r], s[1][r]), fmaxf(s[2][r], s[3][r]));
      v = fmaxf(v, __shfl_xor(v, 1));
      v = fmaxf(v, __shfl_xor(v, 2));
      v = fmaxf(v, __shfl_xor(v, 4));
      v = fmaxf(v, __shfl_xor(v, 8));
      float mn = fmaxf(mrow[r], v);
      al[r] = __expf(mrow[r] - mn);
      mrow[r] = mn;
      moved |= (al[r] != 1.f);
      float sum = 0.f;
      for (int n = 0; n < 4; ++n) {
        float p = __expf(s[n][r] - mn);
        Pw[(quad * 4 + r) * 72 + n * 16 + m16] = f2h(p);
        sum += p;
      }
      sum += __shfl_xor(sum, 1);
      sum += __shfl_xor(sum, 2);
      sum += __shfl_xor(sum, 4);
      sum += __shfl_xor(sum, 8);
      lrow[r] = lrow[r] * al[r] + sum;
    }
    if (__ballot(moved)) {
      for (int i = 0; i < 16; ++i)
        for (int r = 0; r < 4; ++r) O[i][r] *= al[r];
    }
    // PV: P back in A-layout via wave-private LDS
    half8 pf0 = __builtin_bit_cast(half8,
                                   *(const ushort8*)&Pw[m16 * 72 + quad * 8]);
    half8 pf1 = __builtin_bit_cast(
        half8, *(const ushort8*)&Pw[m16 * 72 + 32 + quad * 8]);
    for (int nb = 0; nb < 16; ++nb) {
      half8 vf0 = __builtin_bit_cast(
          half8, *(const ushort8*)&Vs[(nb * 16 + m16) * 72 + quad * 8]);
      O[nb] = __builtin_amdgcn_mfma_f32_16x16x32_f16(pf0, vf0, O[nb], 0, 0, 0);
      half8 vf1 = __builtin_bit_cast(
          half8, *(const ushort8*)&Vs[(nb * 16 + m16) * 72 + 32 + quad * 8]);
      O[nb] = __builtin_amdgcn_mfma_f32_16x16x32_f16(pf1, vf1, O[nb], 0, 0, 0);
    }
  }
#undef LOAD_TILES

  // epilogue: pack f16 partial into d_out (lo/hi u16 per f32 slot)
  unsigned short* o16 = (unsigned short*)out;
  for (int nb = 0; nb < 16; ++nb)
    for (int r = 0; r < 4; ++r) {
      int row = q0 + wave * 16 + quad * 4 + r;
      int col = nb * 16 + m16;
      o16[((base + (size_t)row * DD + col) << 1) + half] = f2h(O[nb][r]);
    }
  if (m16 == 0) {
    float* ml = half ? ml1 : ml0;
    for (int r = 0; r < 4; ++r) {
      int rid = b * LL + q0 + wave * 16 + quad * 4 + r;
      ml[rid * 2] = mrow[r];
      ml[rid * 2 + 1] = lrow[r];
    }
  }
}

// ---------------------------------------------------------------------------
// Kernel 3: merge the two kv-half partials.  grid 256, block 256.
// ---------------------------------------------------------------------------
__global__ __launch_bounds__(256) void merge(
    float* __restrict__ out, const float* __restrict__ ml0,
    const float* __restrict__ ml1) {
  const int t = threadIdx.x;
  const int row0 = blockIdx.x * 64;
  for (int pass = 0; pass < 16; ++pass) {
    int r = row0 + pass * 4 + (t >> 6);
    float m0 = ml0[r * 2], l0 = ml0[r * 2 + 1];
    float m1 = ml1[r * 2], l1 = ml1[r * 2 + 1];
    float m = fmaxf(m0, m1);
    float a0 = __expf(m0 - m), a1 = __expf(m1 - m);
    float inv = 1.f / (l0 * a0 + l1 * a1);
    a0 *= inv;
    a1 *= inv;
    size_t idx = (size_t)r * 64 + (t & 63);
    uint4 u = ((const uint4*)out)[idx];
    float4 o;
    o.x = h2fu(u.x) * a0 + h2fu(u.x >> 16) * a1;
    o.y = h2fu(u.y) * a0 + h2fu(u.y >> 16) * a1;
    o.z = h2fu(u.z) * a0 + h2fu(u.z >> 16) * a1;
    o.w = h2fu(u.w) * a0 + h2fu(u.w >> 16) * a1;
    ((float4*)out)[idx] = o;
  }
}

extern "C" void kernel_launch(void* const* d_in, const int* in_sizes, int n_in,
                              void* d_out, int out_size, void* d_ws, size_t ws_size,
                              hipStream_t stream) {
  const float* x = (const float*)d_in[0];
  const float* Wq = (const float*)d_in[1];
  const float* Wk = (const float*)d_in[2];
  const float* Wv = (const float*)d_in[3];
  const int* lens = (const int*)d_in[4];
  unsigned short* Qb = (unsigned short*)d_ws;
  unsigned short* Kb = Qb + (size_t)BB * LL * DD;
  unsigned short* VT = Kb + (size_t)BB * LL * DD;
  float* ml0 = (float*)(VT + (size_t)BB * LL * DD);
  float* ml1 = ml0 + 2 * BB * LL;
  float* out = (float*)d_out;

  qk_proj<<<dim3(256, 2), 256, 0, stream>>>(x, Wq, Wk, Qb, Kb);
  vproj_t<<<dim3(256), 256, 0, stream>>>(x, Wv, VT);
  attn<<<dim3(32, 8, 2), 256, 0, stream>>>(Qb, Kb, VT, lens, out, ml0, ml1);
  merge<<<256, 256, 0, stream>>>(out, ml0, ml1);
}